// Round 8
// baseline (81.136 us; speedup 1.0000x reference)
//
#include <hip/hip_runtime.h>

// ============================================================================
// PGALoss, analytically reduced:
//   per-point loss = sqrt(1 + d^2) + d,  d = NN distance
//   out = 0.5 * sum_dir clip((mean loss - 1)/2, 0, 1)
// d^2 = min_m(||p||^2 - 2 q.p) + ||q||^2
//
// R8: cost model fitted over R2-R7: total = qloads(12*N*PS scalar VMEM)
// + LDS(evals/(64Q) b128) + VALU(2.0/eval packed) + node overhead.
// => PS=32 (lowest with >=2 blocks/CU), Q=8, fused finalize (last-block
// counter), atomicMin epilogue, 3 graph nodes total.
// ============================================================================

typedef float v2f __attribute__((ext_vector_type(2)));

#define TPB 256
#define Q   8     // queries per thread; QPB = 2048
#define PS  32    // point chunks per task

// ws layout:
//   [0,4)   : uint counter        (memset 0)
//   [64,64+4*QT): uint d2min[QT]  (memset 0x7f -> 3.39e38)

__global__ __launch_bounds__(TPB)
void nn_kernel(const float* __restrict__ src, const float* __restrict__ tgt,
               unsigned int* __restrict__ d2min, unsigned int* __restrict__ counter,
               float* __restrict__ out, int N) {
    __shared__ float4 tA[128];   // {x0,x1,y0,y1} per point-pair
    __shared__ float4 tB[128];   // {z0,z1,w0,w1}

    const int t    = threadIdx.x;
    const int QPB  = TPB * Q;            // 2048
    const int nqc  = N / QPB;            // 4
    const int bpt  = nqc * PS;           // 128
    const int task = blockIdx.x / bpt;   // dir = task>>1, batch = task&1
    const int rem  = blockIdx.x % bpt;
    const int qc   = rem / PS;
    const int pc   = rem % PS;
    const int dir  = task >> 1;
    const int batch= task & 1;
    const int ppb  = N / PS;             // 256 points per block
    const int npairs = ppb / 2;          // 128

    const float* qRaw = (dir ? tgt : src) + (size_t)3 * (batch * N + qc * QPB);
    const float* pRaw = (dir ? src : tgt) + (size_t)3 * (batch * N + pc * ppb);

    // stage 128 point-pairs (threads 0-127)
    for (int i = t; i < npairs; i += TPB) {
        const float* pr = pRaw + 6 * i;
        float x0 = pr[0], y0 = pr[1], z0 = pr[2];
        float x1 = pr[3], y1 = pr[4], z1 = pr[5];
        tA[i] = make_float4(x0, x1, y0, y1);
        tB[i] = make_float4(z0, z1,
                            x0 * x0 + y0 * y0 + z0 * z0,
                            x1 * x1 + y1 * y1 + z1 * z1);
    }

    v2f qx[Q], qy[Q], qz[Q];
    float qq[Q], best0[Q], best1[Q];
    #pragma unroll
    for (int k = 0; k < Q; ++k) {
        const float* qr = qRaw + 3 * (k * TPB + t);
        float x = qr[0], y = qr[1], z = qr[2];
        qx[k] = (v2f){-2.0f * x, -2.0f * x};
        qy[k] = (v2f){-2.0f * y, -2.0f * y};
        qz[k] = (v2f){-2.0f * z, -2.0f * z};
        qq[k] = x * x + y * y + z * z;
        best0[k] = 3.4e38f;
        best1[k] = 3.4e38f;
    }
    __syncthreads();

    #pragma unroll 2
    for (int j = 0; j < npairs; j += 2) {
        float4 a0 = tA[j],     b0 = tB[j];
        float4 a1 = tA[j + 1], b1 = tB[j + 1];
        v2f px0 = (v2f){a0.x, a0.y}, py0 = (v2f){a0.z, a0.w};
        v2f pz0 = (v2f){b0.x, b0.y}, pw0 = (v2f){b0.z, b0.w};
        v2f px1 = (v2f){a1.x, a1.y}, py1 = (v2f){a1.z, a1.w};
        v2f pz1 = (v2f){b1.x, b1.y}, pw1 = (v2f){b1.z, b1.w};
        #pragma unroll
        for (int k = 0; k < Q; ++k) {
            v2f d0 = __builtin_elementwise_fma(px0, qx[k],
                     __builtin_elementwise_fma(py0, qy[k],
                     __builtin_elementwise_fma(pz0, qz[k], pw0)));
            v2f d1 = __builtin_elementwise_fma(px1, qx[k],
                     __builtin_elementwise_fma(py1, qy[k],
                     __builtin_elementwise_fma(pz1, qz[k], pw1)));
            best0[k] = fminf(fminf(d0.x, d1.x), best0[k]);  // v_min3_f32
            best1[k] = fminf(fminf(d0.y, d1.y), best1[k]);
        }
    }

    // per-(query,chunk) min -> global table (order-independent => deterministic)
    const int gqBase = task * N + qc * QPB + t;
    #pragma unroll
    for (int k = 0; k < Q; ++k) {
        float d2 = fmaxf(fminf(best0[k], best1[k]) + qq[k], 0.0f);
        atomicMin(&d2min[gqBase + k * TPB], __float_as_uint(d2));
    }

    // ---- last-block finalize ----
    __shared__ int isLast;
    __shared__ float wsum0[4], wsum1[4];
    __syncthreads();
    if (t == 0) {
        __threadfence();
        unsigned int old = atomicAdd(counter, 1u);
        isLast = (old == gridDim.x - 1) ? 1 : 0;
    }
    __syncthreads();
    if (!isLast) return;
    __threadfence();   // acquire all d2min updates

    const int QT = 4 * N;
    float s0 = 0.0f, s1 = 0.0f;
    for (int i = t; i < QT; i += TPB) {          // 128 iters; dir uniform per iter
        float d2 = __uint_as_float(d2min[i]);
        float f  = sqrtf(1.0f + d2) + sqrtf(d2);
        if (i < 2 * N) s0 += f; else s1 += f;
    }
    for (int o = 32; o > 0; o >>= 1) {
        s0 += __shfl_down(s0, o);
        s1 += __shfl_down(s1, o);
    }
    if ((t & 63) == 0) { wsum0[t >> 6] = s0; wsum1[t >> 6] = s1; }
    __syncthreads();
    if (t == 0) {
        double t0 = (double)wsum0[0] + wsum0[1] + wsum0[2] + wsum0[3];
        double t1 = (double)wsum1[0] + wsum1[1] + wsum1[2] + wsum1[3];
        double inv = 1.0 / (double)(2 * N);
        double l0 = (t0 * inv - 1.0) * 0.5;
        double l1 = (t1 * inv - 1.0) * 0.5;
        l0 = l0 < 0.0 ? 0.0 : (l0 > 1.0 ? 1.0 : l0);
        l1 = l1 < 0.0 ? 0.0 : (l1 > 1.0 ? 1.0 : l1);
        out[0] = (float)(0.5 * (l0 + l1));
    }
}

extern "C" void kernel_launch(void* const* d_in, const int* in_sizes, int n_in,
                              void* d_out, int out_size, void* d_ws, size_t ws_size,
                              hipStream_t stream) {
    const float* src = (const float*)d_in[0];
    const float* tgt = (const float*)d_in[1];
    float* out = (float*)d_out;

    const int twoN = in_sizes[0] / 3;    // 16384
    const int N    = twoN / 2;           // 8192
    const int QT   = 4 * N;              // 32768

    unsigned int* counter = (unsigned int*)d_ws;
    unsigned int* d2min   = (unsigned int*)((char*)d_ws + 64);

    hipMemsetAsync(d_ws, 0, 64, stream);                                  // counter
    hipMemsetAsync(d2min, 0x7f, (size_t)QT * sizeof(unsigned int), stream); // +3.39e38

    const int blocks = 4 * (N / (TPB * Q)) * PS;   // 512
    nn_kernel<<<blocks, TPB, 0, stream>>>(src, tgt, d2min, counter, out, N);
}

// Round 9
// 41.410 us; speedup vs baseline: 1.9594x; 1.9594x over previous
//
#include <hip/hip_runtime.h>

// ============================================================================
// PGALoss, analytically reduced:
//   per-point loss = sqrt(1 + d^2) + d,  d = NN distance
//   out = 0.5 * sum_dir clip((mean loss - 1)/2, 0, 1)
// d^2 = min_m(||p||^2 - 2 q.p) + ||q||^2
//
// R9: R4 skeleton (Q=4, atomicMin merge, parallel reduce) with the two
// R8 lessons applied: no serial finalize tail, and 8 blocks/CU (PS=64,
// 2048 blocks) for latency hiding. Prep kernel pre-packs queries float4
// and points pair-transposed so the PS-scaled prologue is 4 dwordx4
// per thread. 3 kernels, 0 memsets.
// ============================================================================

typedef float v2f __attribute__((ext_vector_type(2)));

#define TPB 256
#define Q   4     // queries per thread; QPB = 1024
#define PS  64    // point chunks per task -> 2048 blocks

// ws layout:
//   [0,4)        : uint counter
//   [16,32)      : double acc[2]
//   [64, +128K)  : uint d2min[4N]          (init 0x7f7f7f7f by prep)
//   [.., +512K)  : float4 P4[4N]           {x,y,z,||.||^2}, order s0,s1,t0,t1
//   [.., +512K)  : float pairBuf[2N pairs * 8]  {x0,x1,y0,y1,z0,z1,w0,w1}

__global__ __launch_bounds__(256)
void prep_kernel(const float* __restrict__ src, const float* __restrict__ tgt,
                 float4* __restrict__ P4, float* __restrict__ pairBuf,
                 unsigned int* __restrict__ d2min, double* __restrict__ acc,
                 unsigned int* __restrict__ counter, int twoN) {
    const int g = blockIdx.x * 256 + threadIdx.x;   // [0, 2*twoN)
    if (g < 2) acc[g] = 0.0;
    if (g == 2) *counter = 0u;
    if (g >= 2 * twoN) return;
    const int which = g >= twoN ? 1 : 0;
    const int i = g - which * twoN;
    const float* in = which ? tgt : src;
    float x = in[3 * i], y = in[3 * i + 1], z = in[3 * i + 2];
    float w = x * x + y * y + z * z;
    P4[g] = make_float4(x, y, z, w);
    d2min[g] = 0x7f7f7f7fu;                         // +3.39e38
    float* pb = pairBuf + (size_t)(g >> 1) * 8 + (g & 1);
    pb[0] = x; pb[2] = y; pb[4] = z; pb[6] = w;
}

__global__ __launch_bounds__(TPB)
void nn_kernel(const float4* __restrict__ P4, const float4* __restrict__ pairT4,
               unsigned int* __restrict__ d2min, int N) {
    __shared__ float4 tA[64];   // {x0,x1,y0,y1} per point-pair
    __shared__ float4 tB[64];   // {z0,z1,w0,w1}

    const int t    = threadIdx.x;
    const int QPB  = TPB * Q;            // 1024
    const int nqc  = N / QPB;            // 8
    const int bpt  = nqc * PS;           // 512
    const int task = blockIdx.x / bpt;   // 0..3 = s0,s1,t0,t1
    const int rem  = blockIdx.x % bpt;
    const int qc   = rem / PS;
    const int pc   = rem % PS;
    const int ppb  = N / PS;             // 128 points per block
    const int npairs = ppb / 2;          // 64

    const float4* qArr = P4 + (size_t)task * N + qc * QPB;
    // point cloud = other input, same batch -> task^2; pair-granular offset
    const float4* pb4 = pairT4 + ((size_t)(task ^ 2) * (N / 2) + (size_t)pc * npairs) * 2;

    // stage 64 point-pairs: 128 float4 loads, threads 0-127
    for (int i = t; i < npairs * 2; i += TPB) {
        float4 v = pb4[i];
        if (i & 1) tB[i >> 1] = v; else tA[i >> 1] = v;
    }

    v2f qx[Q], qy[Q], qz[Q];
    float qq[Q], best0[Q], best1[Q];
    #pragma unroll
    for (int k = 0; k < Q; ++k) {
        float4 q4 = qArr[t + k * TPB];   // one dwordx4 per query
        qx[k] = (v2f){-2.0f * q4.x, -2.0f * q4.x};
        qy[k] = (v2f){-2.0f * q4.y, -2.0f * q4.y};
        qz[k] = (v2f){-2.0f * q4.z, -2.0f * q4.z};
        qq[k] = q4.w;
        best0[k] = 3.4e38f;
        best1[k] = 3.4e38f;
    }
    __syncthreads();

    #pragma unroll 4
    for (int j = 0; j < npairs; j += 2) {
        float4 a0 = tA[j],     b0 = tB[j];
        float4 a1 = tA[j + 1], b1 = tB[j + 1];
        v2f px0 = (v2f){a0.x, a0.y}, py0 = (v2f){a0.z, a0.w};
        v2f pz0 = (v2f){b0.x, b0.y}, pw0 = (v2f){b0.z, b0.w};
        v2f px1 = (v2f){a1.x, a1.y}, py1 = (v2f){a1.z, a1.w};
        v2f pz1 = (v2f){b1.x, b1.y}, pw1 = (v2f){b1.z, b1.w};
        #pragma unroll
        for (int k = 0; k < Q; ++k) {
            v2f d0 = __builtin_elementwise_fma(px0, qx[k],
                     __builtin_elementwise_fma(py0, qy[k],
                     __builtin_elementwise_fma(pz0, qz[k], pw0)));
            v2f d1 = __builtin_elementwise_fma(px1, qx[k],
                     __builtin_elementwise_fma(py1, qy[k],
                     __builtin_elementwise_fma(pz1, qz[k], pw1)));
            best0[k] = fminf(fminf(d0.x, d1.x), best0[k]);  // v_min3_f32
            best1[k] = fminf(fminf(d0.y, d1.y), best1[k]);
        }
    }

    // clamp(min+qq) then merge across point-chunks (order-independent)
    const int gqBase = task * N + qc * QPB + t;
    #pragma unroll
    for (int k = 0; k < Q; ++k) {
        float d2 = fmaxf(fminf(best0[k], best1[k]) + qq[k], 0.0f);
        atomicMin(&d2min[gqBase + k * TPB], __float_as_uint(d2));
    }
}

__global__ __launch_bounds__(256)
void reduce_kernel(const unsigned int* __restrict__ d2min,
                   double* __restrict__ acc, unsigned int* __restrict__ counter,
                   float* __restrict__ out, int N) {
    const int gq = blockIdx.x * 256 + threadIdx.x;   // [0, 4N)
    float d2 = __uint_as_float(d2min[gq]);
    float f  = sqrtf(1.0f + d2) + sqrtf(d2);
    for (int o = 32; o > 0; o >>= 1) f += __shfl_down(f, o);
    const int dir = gq / (2 * N);                    // wave-uniform
    if ((threadIdx.x & 63) == 0) atomicAdd(&acc[dir], (double)f);
    __syncthreads();
    if (threadIdx.x == 0) {
        __threadfence();
        unsigned int old = atomicAdd(counter, 1u);
        if (old == gridDim.x - 1) {                  // last block finalizes
            double s0 = atomicAdd(&acc[0], 0.0);
            double s1 = atomicAdd(&acc[1], 0.0);
            double inv = 1.0 / (double)(2 * N);
            double l0 = (s0 * inv - 1.0) * 0.5;
            double l1 = (s1 * inv - 1.0) * 0.5;
            l0 = l0 < 0.0 ? 0.0 : (l0 > 1.0 ? 1.0 : l0);
            l1 = l1 < 0.0 ? 0.0 : (l1 > 1.0 ? 1.0 : l1);
            out[0] = (float)(0.5 * (l0 + l1));
        }
    }
}

extern "C" void kernel_launch(void* const* d_in, const int* in_sizes, int n_in,
                              void* d_out, int out_size, void* d_ws, size_t ws_size,
                              hipStream_t stream) {
    const float* src = (const float*)d_in[0];
    const float* tgt = (const float*)d_in[1];
    float* out = (float*)d_out;

    const int twoN = in_sizes[0] / 3;    // 16384 points per input
    const int N    = twoN / 2;           // 8192
    const int QT   = 4 * N;              // 32768

    unsigned int* counter = (unsigned int*)d_ws;
    double* acc           = (double*)((char*)d_ws + 16);
    unsigned int* d2min   = (unsigned int*)((char*)d_ws + 64);
    float4* P4            = (float4*)((char*)d_ws + 64 + (size_t)QT * 4);
    float* pairBuf        = (float*)((char*)d_ws + 64 + (size_t)QT * 4 + (size_t)QT * 16);

    prep_kernel<<<(2 * twoN + 255) / 256, 256, 0, stream>>>(
        src, tgt, P4, pairBuf, d2min, acc, counter, twoN);

    const int blocks = 4 * (N / (TPB * Q)) * PS;   // 2048
    nn_kernel<<<blocks, TPB, 0, stream>>>(P4, (const float4*)pairBuf, d2min, N);

    reduce_kernel<<<QT / 256, 256, 0, stream>>>(d2min, acc, counter, out, N);
}

// Round 10
// 36.640 us; speedup vs baseline: 2.2144x; 1.1302x over previous
//
#include <hip/hip_runtime.h>

// ============================================================================
// PGALoss, analytically reduced:
//   per-point loss = sqrt(1 + d^2) + d,  d = NN distance
//   out = 0.5 * sum_dir clip((mean loss - 1)/2, 0, 1)
// d^2 = min_p(||p||^2 - 2 q.p) + ||q||^2
//
// R10: MFMA brute force. pp - 2q.p as one K=16 dot via bf16 hi/lo split:
//   A-row (point):  [-2ph(3), pph, -2ph(3), ppl, -2pl(3), 0, 0(4)]
//   B-col (query):  [ qh(3),  1,    ql(3),  1,    qh(3),  0, 0(4)]
//   sum = pp - 2(qh.ph + ql.ph + qh.pl)   (drops ql.pl ~ 1e-5)
// v_mfma_f32_32x32x16_bf16: D[row=point][col=query] -> min over points is
// IN-LANE (16 regs -> 8 v_min3), epilogue = 1 shfl_xor(32) + atomicMin.
// Zero LDS. Prep packs per-lane fragment packets; reduce as R9.
// ============================================================================

typedef short short8 __attribute__((ext_vector_type(8)));
typedef float f32x16 __attribute__((ext_vector_type(16)));

#define TPB 256
#define PS  8     // point-split: blocks = 4 * (N/256) * PS = 1024

// ws: [0,4) counter | [16,32) acc[2] | [64) d2min[QT] u32 | +QT*4 PParr[QT] f32
//     | +QT*8 Abuf[QT*16 ushort] | +QT*32B Bbuf[QT*16 ushort]

__device__ __forceinline__ unsigned short bf16h(float f) {
    unsigned u = __float_as_uint(f);
    return (unsigned short)((u + 0x7fffu + ((u >> 16) & 1u)) >> 16);
}
__device__ __forceinline__ float bf16v(unsigned short h) {
    return __uint_as_float((unsigned)h << 16);
}

__global__ __launch_bounds__(256)
void prep_kernel(const float* __restrict__ src, const float* __restrict__ tgt,
                 unsigned short* __restrict__ Abuf, unsigned short* __restrict__ Bbuf,
                 float* __restrict__ PParr, unsigned* __restrict__ d2min,
                 double* __restrict__ acc, unsigned* __restrict__ counter, int N) {
    const int g = blockIdx.x * 256 + threadIdx.x;    // [0, 4N)
    if (g < 2) acc[g] = 0.0;
    if (g == 2) *counter = 0u;
    const int QT = 4 * N;
    if (g >= QT) return;
    d2min[g] = 0x7f7f7f7fu;                          // +3.39e38

    const int twoN = 2 * N;
    const float* in = (g >= twoN) ? tgt : src;
    const int i = (g >= twoN) ? (g - twoN) : g;
    const float x = in[3*i], y = in[3*i+1], z = in[3*i+2];
    const float pp = x*x + y*y + z*z;
    PParr[g] = pp;

    alignas(16) unsigned short A16[16];
    alignas(16) unsigned short B16[16];
    const float q[3] = {x, y, z};
    #pragma unroll
    for (int d = 0; d < 3; ++d) {
        unsigned short qh = bf16h(q[d]);
        unsigned short ql = bf16h(q[d] - bf16v(qh));
        B16[d] = qh; B16[4+d] = ql; B16[8+d] = qh;
        const float t = -2.0f * q[d];
        unsigned short th = bf16h(t);
        unsigned short tl = bf16h(t - bf16v(th));
        A16[d] = th; A16[4+d] = th; A16[8+d] = tl;
    }
    const unsigned short pph = bf16h(pp);
    const unsigned short ppl = bf16h(pp - bf16v(pph));
    A16[3] = pph; A16[7] = ppl; A16[11] = 0;
    B16[3] = 0x3F80u; B16[7] = 0x3F80u; B16[11] = 0;  // bf16 1.0
    #pragma unroll
    for (int s = 12; s < 16; ++s) { A16[s] = 0; B16[s] = 0; }

    // fragment packet layout: tile = g>>5 (1024B), row r = g&31:
    //   k-slots 0..7  at tile*512 + r*8   (ushort units)
    //   k-slots 8..15 at tile*512 + 256 + r*8
    const size_t tile = (size_t)(g >> 5), r = (size_t)(g & 31);
    unsigned short* Ad = Abuf + tile * 512 + r * 8;
    unsigned short* Bd = Bbuf + tile * 512 + r * 8;
    *(short8*)(Ad)       = *(const short8*)(A16);
    *(short8*)(Ad + 256) = *(const short8*)(A16 + 8);
    *(short8*)(Bd)       = *(const short8*)(B16);
    *(short8*)(Bd + 256) = *(const short8*)(B16 + 8);
}

__global__ __launch_bounds__(TPB)
void nn_kernel(const unsigned short* __restrict__ Abuf,
               const unsigned short* __restrict__ Bbuf,
               const float* __restrict__ PParr,
               unsigned* __restrict__ d2min, int N) {
    const int tid = threadIdx.x;
    const int l = tid & 63;              // lane
    const int w = tid >> 6;              // wave 0..3
    const int nqc  = N >> 8;             // query chunks (256 q per block)
    const int bpt  = nqc * PS;
    const int task = blockIdx.x / bpt;   // 0..3 = s0,s1,t0,t1
    const int rem  = blockIdx.x % bpt;
    const int qc = rem / PS, pc = rem % PS;

    // per-lane fragment offset (ushort units): half (l>>5), row/col (l&31)
    const size_t laneoff = (size_t)((l >> 5) * 256 + (l & 31) * 8);

    const int qbase = task * N + qc * 256 + w * 64;   // 64 queries per wave
    const size_t qt0 = (size_t)(qbase >> 5);
    const short8 b0 = *(const short8*)(Bbuf + qt0 * 512 + laneoff);
    const short8 b1 = *(const short8*)(Bbuf + (qt0 + 1) * 512 + laneoff);

    const int ppb    = N / PS;                        // 1024 points per block
    const int pbase  = (task ^ 2) * N + pc * ppb;
    const int ntiles = ppb >> 5;                      // 32
    const unsigned short* ap = Abuf + (size_t)(pbase >> 5) * 512 + laneoff;

    float best0 = 3.4e38f, best1 = 3.4e38f;
    const f32x16 z = {};
    #pragma unroll 2
    for (int i = 0; i < ntiles; ++i) {
        const short8 a = *(const short8*)ap;          // A-frag: 32 points x K16
        ap += 512;
        f32x16 d0 = __builtin_amdgcn_mfma_f32_32x32x16_bf16(a, b0, z, 0, 0, 0);
        f32x16 d1 = __builtin_amdgcn_mfma_f32_32x32x16_bf16(a, b1, z, 0, 0, 0);
        best0 = fminf(fminf(d0[0],  d0[1]),  best0);  // v_min3_f32 x8
        best0 = fminf(fminf(d0[2],  d0[3]),  best0);
        best0 = fminf(fminf(d0[4],  d0[5]),  best0);
        best0 = fminf(fminf(d0[6],  d0[7]),  best0);
        best0 = fminf(fminf(d0[8],  d0[9]),  best0);
        best0 = fminf(fminf(d0[10], d0[11]), best0);
        best0 = fminf(fminf(d0[12], d0[13]), best0);
        best0 = fminf(fminf(d0[14], d0[15]), best0);
        best1 = fminf(fminf(d1[0],  d1[1]),  best1);
        best1 = fminf(fminf(d1[2],  d1[3]),  best1);
        best1 = fminf(fminf(d1[4],  d1[5]),  best1);
        best1 = fminf(fminf(d1[6],  d1[7]),  best1);
        best1 = fminf(fminf(d1[8],  d1[9]),  best1);
        best1 = fminf(fminf(d1[10], d1[11]), best1);
        best1 = fminf(fminf(d1[12], d1[13]), best1);
        best1 = fminf(fminf(d1[14], d1[15]), best1);
    }
    // lane holds 16 of 32 point-rows for col (l&31); other 16 rows at lane^32
    best0 = fminf(best0, __shfl_xor(best0, 32));
    best1 = fminf(best1, __shfl_xor(best1, 32));
    if (l < 32) {
        const int q0 = qbase + l;
        const float e0 = fmaxf(best0 + PParr[q0], 0.0f);
        const float e1 = fmaxf(best1 + PParr[q0 + 32], 0.0f);
        atomicMin(&d2min[q0],      __float_as_uint(e0));
        atomicMin(&d2min[q0 + 32], __float_as_uint(e1));
    }
}

__global__ __launch_bounds__(256)
void reduce_kernel(const unsigned* __restrict__ d2min, double* __restrict__ acc,
                   unsigned* __restrict__ counter, float* __restrict__ out, int N) {
    const int gq = blockIdx.x * 256 + threadIdx.x;   // [0, 4N)
    const float d2 = __uint_as_float(d2min[gq]);
    float f = sqrtf(1.0f + d2) + sqrtf(d2);
    for (int o = 32; o > 0; o >>= 1) f += __shfl_down(f, o);
    const int dir = gq / (2 * N);                    // wave-uniform
    if ((threadIdx.x & 63) == 0) atomicAdd(&acc[dir], (double)f);
    __syncthreads();
    if (threadIdx.x == 0) {
        __threadfence();
        const unsigned old = atomicAdd(counter, 1u);
        if (old == gridDim.x - 1) {                  // last block finalizes
            const double s0 = atomicAdd(&acc[0], 0.0);
            const double s1 = atomicAdd(&acc[1], 0.0);
            const double inv = 1.0 / (double)(2 * N);
            double l0 = (s0 * inv - 1.0) * 0.5;
            double l1 = (s1 * inv - 1.0) * 0.5;
            l0 = l0 < 0.0 ? 0.0 : (l0 > 1.0 ? 1.0 : l0);
            l1 = l1 < 0.0 ? 0.0 : (l1 > 1.0 ? 1.0 : l1);
            out[0] = (float)(0.5 * (l0 + l1));
        }
    }
}

extern "C" void kernel_launch(void* const* d_in, const int* in_sizes, int n_in,
                              void* d_out, int out_size, void* d_ws, size_t ws_size,
                              hipStream_t stream) {
    const float* src = (const float*)d_in[0];
    const float* tgt = (const float*)d_in[1];
    float* out = (float*)d_out;

    const int twoN = in_sizes[0] / 3;    // 16384 points per input
    const int N    = twoN / 2;           // 8192
    const int QT   = 4 * N;              // 32768

    unsigned* counter      = (unsigned*)d_ws;
    double* acc            = (double*)((char*)d_ws + 16);
    unsigned* d2min        = (unsigned*)((char*)d_ws + 64);
    float* PParr           = (float*)((char*)d_ws + 64 + (size_t)QT * 4);
    unsigned short* Abuf   = (unsigned short*)((char*)d_ws + 64 + (size_t)QT * 8);
    unsigned short* Bbuf   = Abuf + (size_t)QT * 16;   // QT*32 bytes each

    prep_kernel<<<(QT + 255) / 256, 256, 0, stream>>>(
        src, tgt, Abuf, Bbuf, PParr, d2min, acc, counter, N);

    const int blocks = 4 * (N >> 8) * PS;   // 1024
    nn_kernel<<<blocks, TPB, 0, stream>>>(Abuf, Bbuf, PParr, d2min, N);

    reduce_kernel<<<QT / 256, 256, 0, stream>>>(d2min, acc, counter, out, N);
}